// Round 7
// baseline (366.378 us; speedup 1.0000x reference)
//
#include <hip/hip_runtime.h>
#include <hip/hip_fp16.h>

#define NP    128   // planets per batch
#define NH    64    // hidden dim
#define LDH   72    // slab row stride in f16 elems (16B-aligned rows, 2-way-max banks)
#define ITERS 4     // batches per wave
#define WPB   4     // waves per block

typedef __attribute__((ext_vector_type(8))) _Float16 f16x8;   // MFMA A/B operand, K=32
typedef __attribute__((ext_vector_type(4))) _Float16 f16x4;   // MFMA A/B operand, K=16
typedef __attribute__((ext_vector_type(2))) __fp16  hf16x2;   // return type of cvt_pkrtz
typedef __attribute__((ext_vector_type(4))) float f32x4;

union FragK32 { f16x8 v; unsigned int u[4]; };
union FragK16 { f16x4 v; unsigned int u[2]; };

__device__ __forceinline__ unsigned int pack_pkrtz(float a, float b) {
    hf16x2 t = __builtin_amdgcn_cvt_pkrtz(a, b);
    return __builtin_bit_cast(unsigned int, t);
}

// 256-thread blocks = 4 independent waves; each wave owns ITERS consecutive
// batches and a private LDS slab double-buffer. No __syncthreads anywhere;
// slab write->read ordering is per-wave via s_waitcnt lgkmcnt(0).
__global__ void __launch_bounds__(256, 4) gnn_wave(
    const float* __restrict__ planet_xy,  // [B][P][2]
    const float* __restrict__ planet_m,   // [P]
    const float* __restrict__ ast_xy,     // [B][2]
    const float* __restrict__ W1,         // [4][64]
    const float* __restrict__ b1,         // [64]
    const float* __restrict__ W2,         // [64][64]
    const float* __restrict__ b2,         // [64]
    float* __restrict__ out)              // [B][64]
{
    __shared__ alignas(16) unsigned short slab[WPB][2][16 * LDH];

    const int tid  = threadIdx.x;
    const int wv   = tid >> 6;
    const int lane = tid & 63;
    const int q    = lane >> 4;
    const int lm   = lane & 15;
    const bool q0  = (q == 0);
    const bool q1  = (q == 1);

    // ---- layer1 weight fragments (16x16x16f16), b1 FOLDED as feature k=4 ----
    // A[m=16mt+lm][k=4q+j]: k<4 -> W1[k][m]; k==4 (q==1,j==0) -> b1[m]; else 0.
    FragK16 w1f[4];
    #pragma unroll
    for (int mt = 0; mt < 4; mt++) {
        const int m = 16 * mt + lm;
        float wa = W1[0 * NH + m], wb = W1[1 * NH + m];
        float wc = W1[2 * NH + m], wd = W1[3 * NH + m];
        float be = b1[m];
        w1f[mt].u[0] = q0 ? pack_pkrtz(wa, wb) : (q1 ? pack_pkrtz(be, 0.f) : 0u);
        w1f[mt].u[1] = q0 ? pack_pkrtz(wc, wd) : 0u;
    }

    // ---- layer2 weight fragments (16x16x32): B[k=32kk+8q+j][n=16np+lm] ----
    FragK32 w2f[2][4];
    #pragma unroll
    for (int kk = 0; kk < 2; kk++)
        #pragma unroll
        for (int np = 0; np < 4; np++)
            #pragma unroll
            for (int jp = 0; jp < 4; jp++) {
                float r0 = W2[(32 * kk + 8 * q + 2 * jp + 0) * NH + 16 * np + lm];
                float r1 = W2[(32 * kk + 8 * q + 2 * jp + 1) * NH + 16 * np + lm];
                w2f[kk][np].u[jp] = pack_pkrtz(r0, r1);
            }

    // b2 as layer2 C-init (col = 16np+lm, same for all 4 row-regs)
    f32x4 b2f[4];
    #pragma unroll
    for (int np = 0; np < 4; np++) {
        float v = b2[16 * np + lm];
        b2f[np] = (f32x4){v, v, v, v};
    }

    // batch-invariant planet masses (planet 16*i + lm)
    float pmv[8];
    #pragma unroll
    for (int i = 0; i < 8; i++)
        pmv[i] = planet_m[16 * i + lm];

    const f32x4 zf = (f32x4){0.f, 0.f, 0.f, 0.f};
    int b = (blockIdx.x * WPB + wv) * ITERS;

    for (int it = 0; it < ITERS; ++it, ++b) {
        const float2 axy = *(const float2*)&ast_xy[2 * b];
        float2 pxy[8];
        #pragma unroll
        for (int i = 0; i < 8; i++)
            pxy[i] = *(const float2*)&planet_xy[((size_t)b * NP + 16 * i + lm) * 2];

        float sums[4] = {0.f, 0.f, 0.f, 0.f};

        // ---- slab 0: layer1 for planets 0..15 ----
        {
            float dx = pxy[0].x - axy.x, dy = pxy[0].y - axy.y;
            float inv = __builtin_amdgcn_rsqf(fmaf(dx, dx, fmaf(dy, dy, 1e-6f)));
            FragK16 bf;
            bf.u[0] = q0 ? pack_pkrtz(dx, dy)      : (q1 ? pack_pkrtz(1.f, 0.f) : 0u);
            bf.u[1] = q0 ? pack_pkrtz(inv, pmv[0]) : 0u;
            #pragma unroll
            for (int mt = 0; mt < 4; mt++) {
                f32x4 c = __builtin_amdgcn_mfma_f32_16x16x16f16(w1f[mt].v, bf.v, zf, 0, 0, 0);
                unsigned int d0 = pack_pkrtz(fmaxf(c[0], 0.f), fmaxf(c[1], 0.f));
                unsigned int d1 = pack_pkrtz(fmaxf(c[2], 0.f), fmaxf(c[3], 0.f));
                *(uint2*)&slab[wv][0][lm * LDH + 4 * q + 16 * mt] = make_uint2(d0, d1);
            }
        }

        #pragma unroll
        for (int mi = 0; mi < 8; ++mi) {
            const int buf = mi & 1;
            // per-wave ordering: slab writes above must land before reads below
            asm volatile("s_waitcnt lgkmcnt(0)" ::: "memory");
            f16x8 a0 = *(const f16x8*)&slab[wv][buf][lm * LDH + 0  + 8 * q];
            f16x8 a1 = *(const f16x8*)&slab[wv][buf][lm * LDH + 32 + 8 * q];

            // produce next slab while the reads are in flight
            if (mi < 7) {
                float dx = pxy[mi + 1].x - axy.x, dy = pxy[mi + 1].y - axy.y;
                float inv = __builtin_amdgcn_rsqf(fmaf(dx, dx, fmaf(dy, dy, 1e-6f)));
                FragK16 bf;
                bf.u[0] = q0 ? pack_pkrtz(dx, dy)           : (q1 ? pack_pkrtz(1.f, 0.f) : 0u);
                bf.u[1] = q0 ? pack_pkrtz(inv, pmv[mi + 1]) : 0u;
                #pragma unroll
                for (int mt = 0; mt < 4; mt++) {
                    f32x4 c = __builtin_amdgcn_mfma_f32_16x16x16f16(w1f[mt].v, bf.v, zf, 0, 0, 0);
                    unsigned int d0 = pack_pkrtz(fmaxf(c[0], 0.f), fmaxf(c[1], 0.f));
                    unsigned int d1 = pack_pkrtz(fmaxf(c[2], 0.f), fmaxf(c[3], 0.f));
                    *(uint2*)&slab[wv][buf ^ 1][lm * LDH + 4 * q + 16 * mt] = make_uint2(d0, d1);
                }
            }

            // layer2: 16-planet x 64-col tile, bias via C-operand
            #pragma unroll
            for (int np = 0; np < 4; np++) {
                f32x4 acc = __builtin_amdgcn_mfma_f32_16x16x32_f16(a0, w2f[0][np].v, b2f[np], 0, 0, 0);
                acc = __builtin_amdgcn_mfma_f32_16x16x32_f16(a1, w2f[1][np].v, acc, 0, 0, 0);
                sums[np] += fmaxf(acc[0], 0.f);
                sums[np] += fmaxf(acc[1], 0.f);
                sums[np] += fmaxf(acc[2], 0.f);
                sums[np] += fmaxf(acc[3], 0.f);
            }
        }

        // ---- cross-quad reduction + store ----
        #pragma unroll
        for (int np = 0; np < 4; np++) {
            float s = sums[np];
            s += __shfl_xor(s, 16, 64);
            s += __shfl_xor(s, 32, 64);
            if (q0) out[(size_t)b * NH + 16 * np + lm] = s;
        }
    }
}

extern "C" void kernel_launch(void* const* d_in, const int* in_sizes, int n_in,
                              void* d_out, int out_size, void* d_ws, size_t ws_size,
                              hipStream_t stream) {
    const float* planet_xy = (const float*)d_in[0];
    const float* planet_m  = (const float*)d_in[1];
    const float* ast_xy    = (const float*)d_in[2];
    const float* W1        = (const float*)d_in[3];
    const float* b1        = (const float*)d_in[4];
    const float* W2        = (const float*)d_in[5];
    const float* b2        = (const float*)d_in[6];
    float* outp            = (float*)d_out;

    const int B = in_sizes[2] / 2;   // ast_xy is [B][2]
    const int batches_per_block = WPB * ITERS;
    const int grid = (B + batches_per_block - 1) / batches_per_block;

    gnn_wave<<<grid, 256, 0, stream>>>(planet_xy, planet_m, ast_xy, W1, b1, W2, b2, outp);
}

// Round 8
// 148.429 us; speedup vs baseline: 2.4684x; 2.4684x over previous
//
#include <hip/hip_runtime.h>
#include <hip/hip_fp16.h>

#define NP    128   // planets per batch
#define NH    64    // hidden dim
#define LDH   72    // slab row stride in f16 elems (16B-aligned rows, 2-way-max banks)
#define ITERS 4     // batches per wave
#define WPB   4     // waves per block

typedef __attribute__((ext_vector_type(8))) _Float16 f16x8;   // MFMA A/B operand, K=32
typedef __attribute__((ext_vector_type(4))) _Float16 f16x4;   // MFMA A/B operand, K=16
typedef __attribute__((ext_vector_type(2))) __fp16  hf16x2;   // return type of cvt_pkrtz
typedef __attribute__((ext_vector_type(4))) float f32x4;

union FragK32 { f16x8 v; unsigned int u[4]; };
union FragK16 { f16x4 v; unsigned int u[2]; };

__device__ __forceinline__ unsigned int pack_pkrtz(float a, float b) {
    hf16x2 t = __builtin_amdgcn_cvt_pkrtz(a, b);
    return __builtin_bit_cast(unsigned int, t);
}

// 256-thread blocks = 4 independent waves; each wave owns ITERS consecutive
// batches and a private LDS slab double-buffer. No __syncthreads anywhere;
// slab write->read ordering is per-wave via s_waitcnt lgkmcnt(0).
// launch_bounds (256, 2): VGPR cap 256 — this kernel NEEDS ~110-130 arch VGPRs;
// tighter caps (R6: 84, R7: 64) caused 78-404 MB of scratch spill traffic.
__global__ void __launch_bounds__(256, 2) gnn_wave(
    const float* __restrict__ planet_xy,  // [B][P][2]
    const float* __restrict__ planet_m,   // [P]
    const float* __restrict__ ast_xy,     // [B][2]
    const float* __restrict__ W1,         // [4][64]
    const float* __restrict__ b1,         // [64]
    const float* __restrict__ W2,         // [64][64]
    const float* __restrict__ b2,         // [64]
    float* __restrict__ out)              // [B][64]
{
    __shared__ alignas(16) unsigned short slab[WPB][2][16 * LDH];

    const int tid  = threadIdx.x;
    const int wv   = tid >> 6;
    const int lane = tid & 63;
    const int q    = lane >> 4;
    const int lm   = lane & 15;
    const bool q0  = (q == 0);
    const bool q1  = (q == 1);

    // ---- layer1 weight fragments (16x16x16f16), b1 FOLDED as feature k=4 ----
    // A[m=16mt+lm][k=4q+j]: k<4 -> W1[k][m]; k==4 (q==1,j==0) -> b1[m]; else 0.
    FragK16 w1f[4];
    #pragma unroll
    for (int mt = 0; mt < 4; mt++) {
        const int m = 16 * mt + lm;
        float wa = W1[0 * NH + m], wb = W1[1 * NH + m];
        float wc = W1[2 * NH + m], wd = W1[3 * NH + m];
        float be = b1[m];
        w1f[mt].u[0] = q0 ? pack_pkrtz(wa, wb) : (q1 ? pack_pkrtz(be, 0.f) : 0u);
        w1f[mt].u[1] = q0 ? pack_pkrtz(wc, wd) : 0u;
    }

    // ---- layer2 weight fragments (16x16x32): B[k=32kk+8q+j][n=16np+lm] ----
    FragK32 w2f[2][4];
    #pragma unroll
    for (int kk = 0; kk < 2; kk++)
        #pragma unroll
        for (int np = 0; np < 4; np++)
            #pragma unroll
            for (int jp = 0; jp < 4; jp++) {
                float r0 = W2[(32 * kk + 8 * q + 2 * jp + 0) * NH + 16 * np + lm];
                float r1 = W2[(32 * kk + 8 * q + 2 * jp + 1) * NH + 16 * np + lm];
                w2f[kk][np].u[jp] = pack_pkrtz(r0, r1);
            }

    // b2 as layer2 C-init (col = 16np+lm, same for all 4 row-regs)
    f32x4 b2f[4];
    #pragma unroll
    for (int np = 0; np < 4; np++) {
        float v = b2[16 * np + lm];
        b2f[np] = (f32x4){v, v, v, v};
    }

    // batch-invariant planet masses (planet 16*i + lm)
    float pmv[8];
    #pragma unroll
    for (int i = 0; i < 8; i++)
        pmv[i] = planet_m[16 * i + lm];

    const f32x4 zf = (f32x4){0.f, 0.f, 0.f, 0.f};
    int b = (blockIdx.x * WPB + wv) * ITERS;

    for (int it = 0; it < ITERS; ++it, ++b) {
        const float2 axy = *(const float2*)&ast_xy[2 * b];
        float2 pxy[8];
        #pragma unroll
        for (int i = 0; i < 8; i++)
            pxy[i] = *(const float2*)&planet_xy[((size_t)b * NP + 16 * i + lm) * 2];

        float sums[4] = {0.f, 0.f, 0.f, 0.f};

        // ---- slab 0: layer1 for planets 0..15 ----
        {
            float dx = pxy[0].x - axy.x, dy = pxy[0].y - axy.y;
            float inv = __builtin_amdgcn_rsqf(fmaf(dx, dx, fmaf(dy, dy, 1e-6f)));
            FragK16 bf;
            bf.u[0] = q0 ? pack_pkrtz(dx, dy)      : (q1 ? pack_pkrtz(1.f, 0.f) : 0u);
            bf.u[1] = q0 ? pack_pkrtz(inv, pmv[0]) : 0u;
            #pragma unroll
            for (int mt = 0; mt < 4; mt++) {
                f32x4 c = __builtin_amdgcn_mfma_f32_16x16x16f16(w1f[mt].v, bf.v, zf, 0, 0, 0);
                unsigned int d0 = pack_pkrtz(fmaxf(c[0], 0.f), fmaxf(c[1], 0.f));
                unsigned int d1 = pack_pkrtz(fmaxf(c[2], 0.f), fmaxf(c[3], 0.f));
                *(uint2*)&slab[wv][0][lm * LDH + 4 * q + 16 * mt] = make_uint2(d0, d1);
            }
        }

        #pragma unroll
        for (int mi = 0; mi < 8; ++mi) {
            const int buf = mi & 1;
            // per-wave ordering: slab writes above must land before reads below
            asm volatile("s_waitcnt lgkmcnt(0)" ::: "memory");
            f16x8 a0 = *(const f16x8*)&slab[wv][buf][lm * LDH + 0  + 8 * q];
            f16x8 a1 = *(const f16x8*)&slab[wv][buf][lm * LDH + 32 + 8 * q];

            // produce next slab while the reads are in flight
            if (mi < 7) {
                float dx = pxy[mi + 1].x - axy.x, dy = pxy[mi + 1].y - axy.y;
                float inv = __builtin_amdgcn_rsqf(fmaf(dx, dx, fmaf(dy, dy, 1e-6f)));
                FragK16 bf;
                bf.u[0] = q0 ? pack_pkrtz(dx, dy)           : (q1 ? pack_pkrtz(1.f, 0.f) : 0u);
                bf.u[1] = q0 ? pack_pkrtz(inv, pmv[mi + 1]) : 0u;
                #pragma unroll
                for (int mt = 0; mt < 4; mt++) {
                    f32x4 c = __builtin_amdgcn_mfma_f32_16x16x16f16(w1f[mt].v, bf.v, zf, 0, 0, 0);
                    unsigned int d0 = pack_pkrtz(fmaxf(c[0], 0.f), fmaxf(c[1], 0.f));
                    unsigned int d1 = pack_pkrtz(fmaxf(c[2], 0.f), fmaxf(c[3], 0.f));
                    *(uint2*)&slab[wv][buf ^ 1][lm * LDH + 4 * q + 16 * mt] = make_uint2(d0, d1);
                }
            }

            // layer2: 16-planet x 64-col tile, bias via C-operand
            #pragma unroll
            for (int np = 0; np < 4; np++) {
                f32x4 acc = __builtin_amdgcn_mfma_f32_16x16x32_f16(a0, w2f[0][np].v, b2f[np], 0, 0, 0);
                acc = __builtin_amdgcn_mfma_f32_16x16x32_f16(a1, w2f[1][np].v, acc, 0, 0, 0);
                sums[np] += fmaxf(acc[0], 0.f);
                sums[np] += fmaxf(acc[1], 0.f);
                sums[np] += fmaxf(acc[2], 0.f);
                sums[np] += fmaxf(acc[3], 0.f);
            }
        }

        // ---- cross-quad reduction + store ----
        #pragma unroll
        for (int np = 0; np < 4; np++) {
            float s = sums[np];
            s += __shfl_xor(s, 16, 64);
            s += __shfl_xor(s, 32, 64);
            if (q0) out[(size_t)b * NH + 16 * np + lm] = s;
        }
    }
}

extern "C" void kernel_launch(void* const* d_in, const int* in_sizes, int n_in,
                              void* d_out, int out_size, void* d_ws, size_t ws_size,
                              hipStream_t stream) {
    const float* planet_xy = (const float*)d_in[0];
    const float* planet_m  = (const float*)d_in[1];
    const float* ast_xy    = (const float*)d_in[2];
    const float* W1        = (const float*)d_in[3];
    const float* b1        = (const float*)d_in[4];
    const float* W2        = (const float*)d_in[5];
    const float* b2        = (const float*)d_in[6];
    float* outp            = (float*)d_out;

    const int B = in_sizes[2] / 2;   // ast_xy is [B][2]
    const int batches_per_block = WPB * ITERS;
    const int grid = (B + batches_per_block - 1) / batches_per_block;

    gnn_wave<<<grid, 256, 0, stream>>>(planet_xy, planet_m, ast_xy, W1, b1, W2, b2, outp);
}